// Round 3
// baseline (1623.539 us; speedup 1.0000x reference)
//
#include <hip/hip_runtime.h>
#include <cstddef>
#include <cstdint>

// RIMCell fused pipeline for MI355X (gfx950), dtype-robust (f32 or bf16 inputs).
// Scores path (top-k critical) uses 3-way bf16 split on MFMA (product error
// ~2^-25 rel): A' sections [h,h,m,h,l,m] x B' sections [h,m,h,l,h,m].

typedef unsigned short u16;
typedef __bf16 bf16x8 __attribute__((ext_vector_type(8)));
typedef float f32x4 __attribute__((ext_vector_type(4)));
typedef u16 u16x4 __attribute__((ext_vector_type(4)));

#define DEVFN static __device__ __forceinline__

DEVFN float ldin(const void* p, size_t i, int f) {
  return f ? (float)reinterpret_cast<const __bf16*>(p)[i]
           : reinterpret_cast<const float*>(p)[i];
}
DEVFN float bf2f(const u16* p, size_t i) {
  return (float)reinterpret_cast<const __bf16*>(p)[i];
}
DEVFN void f2bf(u16* p, size_t i, float v) {
  reinterpret_cast<__bf16*>(p)[i] = (__bf16)v;
}
DEVFN u16 bfbits(float v) {
  __bf16 b = (__bf16)v;
  return *reinterpret_cast<u16*>(&b);
}

// ---------------- ws layout (bytes) ----------------
constexpr size_t OFF_FLAG = 0;
constexpr size_t OFF_MASK = 256;        // 4096*6*4 = 98304
constexpr size_t OFF_WVT  = 98560;      // 400*1024*2 = 819200
constexpr size_t OFF_WQKT = 917760;     // 6*256*512*2 = 1572864
constexpr size_t OFF_WVT_ = 2490624;    // 6*2048*512*2 = 12582912
constexpr size_t OFF_WOT  = 15073536;   // 6*512*2048*2 = 12582912
constexpr size_t OFF_WXCT = 27656448;   // 6*1536*400*2 = 7372800
constexpr size_t OFF_WHCT = 35029248;   // 6*1536*512*2 = 9437184
constexpr size_t OFF_HY   = 44466432;   // 4096*3072*2 = 25165824
constexpr size_t OFF_WKC  = 69632256;   // 64*6144*2 = 786432
constexpr size_t OFF_WQC  = 70418688;   // 6*64*3072*2 = 2359296
constexpr size_t ARENA    = 72777984;
constexpr size_t A_INP    = ARENA;      // inputs bf16 4096*2400*2 = 19660800
constexpr size_t A_P1     = 92438784;
constexpr size_t A_KL     = A_P1;       // k_l0 f32 4096*64*4 = 1048576
constexpr size_t A_QL     = 93487360;   // q_l f32 4096*384*4 = 6291456
constexpr size_t A_VL     = 99778816;   // v_l0 bf16 4096*400*2 = 3276800
// P2 chunk: Ggx at A_P1, Ggh at A_P1 + R2*18432 (needs A_P1 + R2*36864)
// P3 chunk: qk at ARENA, v at +R3*3072, ctx at +R3*3072+R3*24576

// ---------------- dtype detection ----------------
__global__ void rim_detect(const void* sw, int* flagp) {
  if (threadIdx.x == 0) {
    float s = 0.f;
    for (int i = 0; i < 24; i++)
      s += (float)reinterpret_cast<const __bf16*>(sw)[i];
    flagp[0] = (s > 5.5f && s < 6.5f) ? 1 : 0;
  }
}

// ---------------- GEMM: C = A @ Bt^T, 128x128 tile, mfma 16x16x32 bf16 -------
// ADT: 0 ws bf16, 1 original input (dual dtype), 2 original input with 3-way
//      split K-expansion (sections of KP: A pattern [h,h,m,h,l,m]).
// EPI: 0 f32, 1 f32+bias(orig), 2 bf16+bias(orig), 3 bf16, 4 final select.
template<int EPI, int ADT>
__global__ __launch_bounds__(256)
void rim_gemm(const void* __restrict__ A_, long A0, long lda, long Az,
              const u16* __restrict__ B_, long Bz,
              void* __restrict__ C_, long C0, long ldc, long Cz,
              int M, int N, int K, int KP,
              const void* __restrict__ bias,
              const u16* __restrict__ hyp,
              const float* __restrict__ maskp,
              const void* __restrict__ hsp,
              const int* __restrict__ flagp)
{
  __shared__ __align__(16) __bf16 As[128 * 32];
  __shared__ __align__(16) __bf16 Bs[128 * 32];
  const int f = flagp[0];
  const int t = threadIdx.x;
  const int m0 = blockIdx.x * 128, n0 = blockIdx.y * 128, z = blockIdx.z;
  const __bf16* Bb = reinterpret_cast<const __bf16*>(B_) + (size_t)z * Bz;
  const int lane = t & 63, w = t >> 6;
  const int wm = (w & 1) * 64, wn = (w >> 1) * 64;
  const int lr = lane & 15, lk = (lane >> 4) * 8;

  f32x4 acc[4][4];
#pragma unroll
  for (int i = 0; i < 4; i++)
#pragma unroll
    for (int j = 0; j < 4; j++)
#pragma unroll
      for (int r = 0; r < 4; r++) acc[i][j][r] = 0.f;

  const int r0 = t >> 2;
  const int kc0 = (t & 3) << 3;

  for (int k0 = 0; k0 < K; k0 += 32) {
#pragma unroll
    for (int it = 0; it < 2; it++) {
      int row = r0 + it * 64;
      int gk = k0 + kc0;
      bf16x8 av, bv8;
#pragma unroll
      for (int q = 0; q < 8; q++) { av[q] = (__bf16)0.f; bv8[q] = (__bf16)0.f; }
      int gm = m0 + row;
      if (gm < M && gk < K) {
        if constexpr (ADT == 0) {
          av = *reinterpret_cast<const bf16x8*>(
              reinterpret_cast<const __bf16*>(A_) + (size_t)A0 + (size_t)z * Az +
              (size_t)gm * lda + gk);
        } else if constexpr (ADT == 1) {
          size_t idx = (size_t)A0 + (size_t)z * Az + (size_t)gm * lda + gk;
          if (f) {
            av = *reinterpret_cast<const bf16x8*>(
                reinterpret_cast<const __bf16*>(A_) + idx);
          } else {
            const f32x4* fp = reinterpret_cast<const f32x4*>(
                reinterpret_cast<const float*>(A_) + idx);
            f32x4 lo = fp[0], hi = fp[1];
#pragma unroll
            for (int q = 0; q < 4; q++) {
              av[q] = (__bf16)lo[q]; av[q + 4] = (__bf16)hi[q];
            }
          }
        } else {  // ADT == 2: 3-way split, sections of KP
          int sec = gk / KP, kk = gk - sec * KP;
          size_t idx = (size_t)A0 + (size_t)z * Az + (size_t)gm * lda + kk;
          if (f) {
            // bf16 input: h=v, m=l=0; A pattern: secs 0,1,3 = h
            if (sec == 0 || sec == 1 || sec == 3)
              av = *reinterpret_cast<const bf16x8*>(
                  reinterpret_cast<const __bf16*>(A_) + idx);
          } else {
            const f32x4* fp = reinterpret_cast<const f32x4*>(
                reinterpret_cast<const float*>(A_) + idx);
            f32x4 v4a = fp[0], v4b = fp[1];
#pragma unroll
            for (int q = 0; q < 8; q++) {
              float v = (q < 4) ? v4a[q] : v4b[q - 4];
              __bf16 h = (__bf16)v;
              float r1 = v - (float)h;
              __bf16 m = (__bf16)r1;
              float r2 = r1 - (float)m;
              __bf16 l = (__bf16)r2;
              av[q] = (sec == 0 || sec == 1 || sec == 3) ? h
                      : (sec == 2 || sec == 5) ? m : l;
            }
          }
        }
      }
      int gn = n0 + row;
      if (gn < N && gk < K)
        bv8 = *reinterpret_cast<const bf16x8*>(Bb + (size_t)gn * (size_t)K + gk);
      *reinterpret_cast<bf16x8*>(&As[row * 32 + kc0]) = av;
      *reinterpret_cast<bf16x8*>(&Bs[row * 32 + kc0]) = bv8;
    }
    __syncthreads();
    bf16x8 af[4], bg[4];
#pragma unroll
    for (int i = 0; i < 4; i++)
      af[i] = *reinterpret_cast<const bf16x8*>(&As[(wm + i * 16 + lr) * 32 + lk]);
#pragma unroll
    for (int j = 0; j < 4; j++)
      bg[j] = *reinterpret_cast<const bf16x8*>(&Bs[(wn + j * 16 + lr) * 32 + lk]);
#pragma unroll
    for (int i = 0; i < 4; i++)
#pragma unroll
      for (int j = 0; j < 4; j++)
        acc[i][j] = __builtin_amdgcn_mfma_f32_16x16x32_bf16(af[i], bg[j], acc[i][j], 0, 0, 0);
    __syncthreads();
  }

  const int rq = (lane >> 4) * 4;  // C/D: row=(lane>>4)*4+reg, col=lane&15
  const int cq = lane & 15;
#pragma unroll
  for (int i = 0; i < 4; i++) {
#pragma unroll
    for (int j = 0; j < 4; j++) {
      int cg = n0 + wn + j * 16 + cq;
      if (cg >= N) continue;
#pragma unroll
      for (int r = 0; r < 4; r++) {
        int rg = m0 + wm + i * 16 + rq + r;
        if (rg >= M) continue;
        float v = acc[i][j][r];
        size_t cidx = (size_t)rg * ldc + (size_t)z * Cz + cg;
        if constexpr (EPI == 0) {
          reinterpret_cast<float*>(C_)[C0 + cidx] = v;
        } else if constexpr (EPI == 1) {
          reinterpret_cast<float*>(C_)[C0 + cidx] = v + ldin(bias, cg, f);
        } else if constexpr (EPI == 2) {
          f2bf((u16*)C_, C0 + cidx, v + ldin(bias, cg, f));
        } else if constexpr (EPI == 3) {
          f2bf((u16*)C_, C0 + cidx, v);
        } else {
          float mk = maskp[(size_t)rg * 6 + z];
          if (mk > 0.5f) {
            float o = v + bf2f(hyp, cidx);
            if (f) f2bf((u16*)C_, C0 + cidx, o);
            else   reinterpret_cast<float*>(C_)[C0 + cidx] = o;
          } else {
            if (f) reinterpret_cast<u16*>(C_)[C0 + cidx] =
                       reinterpret_cast<const u16*>(hsp)[C0 + cidx];
            else   reinterpret_cast<float*>(C_)[C0 + cidx] =
                       reinterpret_cast<const float*>(hsp)[C0 + cidx];
          }
        }
      }
    }
  }
}

// ------- tiled transpose to bf16: out[z][n][k] = cvt(in[z][k][n]) -----------
__global__ __launch_bounds__(256)
void rim_transpose(const void* __restrict__ in, u16* __restrict__ out,
                   int N, int K, long in_z, long out_z,
                   const int* __restrict__ flagp)
{
  const int f = flagp[0];
  __shared__ float tile[32][33];
  int z = blockIdx.z;
  int k0 = blockIdx.x * 32, n0 = blockIdx.y * 32;
  int c = threadIdx.x & 31, r = threadIdx.x >> 5;
  for (int rr = r; rr < 32; rr += 8) {
    int k = k0 + rr, n = n0 + c;
    tile[rr][c] = (k < K && n < N)
        ? ldin(in, (size_t)z * in_z + (size_t)k * N + n, f) : 0.f;
  }
  __syncthreads();
  for (int rr = r; rr < 32; rr += 8) {
    int n = n0 + rr, k = k0 + c;
    if (n < N && k < K)
      f2bf(out, (size_t)z * out_z + (size_t)n * K + k, tile[c][rr]);
  }
}

// ------- weight 3-way-split concat: out[z][n][s*K+k] = Bsplit_s(W[z][k][n]) --
// B pattern: [h, m, h, l, h, m]
__global__ void rim_wcat(const void* __restrict__ W, u16* __restrict__ out,
                         int N, int K, long wz, long oz, long total,
                         const int* __restrict__ flagp)
{
  const int f = flagp[0];
  long idx = (long)blockIdx.x * 256 + threadIdx.x;
  if (idx >= total) return;
  long n = idx % N;
  long t2 = idx / N;
  long k = t2 % K;
  long z = t2 / K;
  float v = ldin(W, z * wz + k * N + n, f);
  __bf16 h = (__bf16)v;
  float r1 = v - (float)h;
  __bf16 m = (__bf16)r1;
  float r2 = r1 - (float)m;
  __bf16 l = (__bf16)r2;
  u16 hb = *reinterpret_cast<u16*>(&h);
  u16 mb = *reinterpret_cast<u16*>(&m);
  u16 lb = *reinterpret_cast<u16*>(&l);
  u16* ob = out + z * oz + n * (long)(6 * K) + k;
  ob[0 * K] = hb; ob[1 * K] = mb; ob[2 * K] = hb;
  ob[3 * K] = lb; ob[4 * K] = hb; ob[5 * K] = mb;
}

// ------- combined GRU weight, tiled transpose: out[u][o][i]=sum_s sw*gw[s][i][o]
__global__ __launch_bounds__(256)
void rim_gruw(const void* __restrict__ sw, const void* __restrict__ gw,
              u16* __restrict__ out, int IVH, const int* __restrict__ flagp)
{
  const int f = flagp[0];
  __shared__ float lds[64 * 17];
  int u = blockIdx.z;
  int i0 = blockIdx.x * 16, o0 = blockIdx.y * 64;
  int t = threadIdx.x;
  float s0 = ldin(sw, u * 4 + 0, f), s1 = ldin(sw, u * 4 + 1, f);
  float s2 = ldin(sw, u * 4 + 2, f), s3 = ldin(sw, u * 4 + 3, f);
  int oo = t & 63, iq = t >> 6;
  size_t pl = (size_t)IVH * 1536;
#pragma unroll
  for (int r = 0; r < 4; r++) {
    int ii = iq * 4 + r;
    size_t base = (size_t)(i0 + ii) * 1536 + o0 + oo;
    float acc = s0 * ldin(gw, base, f) + s1 * ldin(gw, pl + base, f) +
                s2 * ldin(gw, 2 * pl + base, f) + s3 * ldin(gw, 3 * pl + base, f);
    lds[oo * 17 + ii] = acc;
  }
  __syncthreads();
  int ow = t >> 2, iw = (t & 3) * 4;
  u16x4 pk;
#pragma unroll
  for (int j = 0; j < 4; j++) pk[j] = bfbits(lds[ow * 17 + iw + j]);
  *reinterpret_cast<u16x4*>(out + ((size_t)u * 1536 + o0 + ow) * IVH + i0 + iw) = pk;
}

// ---------------- scores / top-4 mask / 2-way softmax / inputs ----------------
__global__ __launch_bounds__(256)
void rim_scores(const float* __restrict__ q_l, const float* __restrict__ k_l0,
                const void* __restrict__ bk, const u16* __restrict__ v_l0,
                const void* __restrict__ bv, float* __restrict__ maskf,
                u16* __restrict__ inputs, const int* __restrict__ flagp)
{
  const int f = flagp[0];
  int b = blockIdx.x;
  int t = threadIdx.x;
  int lane = t & 63;
  __shared__ float s0[6], s1[6], sm[6], sp[6];
  if (t < 64) {
    float kv = k_l0[(size_t)b * 64 + lane];
    for (int u = 0; u < 6; u++) {
      float p = q_l[((size_t)b * 6 + u) * 64 + lane] * kv;
      for (int off = 32; off; off >>= 1) p += __shfl_down(p, off);
      if (lane == 0) s0[u] = p * 0.125f;
    }
  } else if (t < 128) {
    float kv = ldin(bk, lane, f);
    for (int u = 0; u < 6; u++) {
      float p = q_l[((size_t)b * 6 + u) * 64 + lane] * kv;
      for (int off = 32; off; off >>= 1) p += __shfl_down(p, off);
      if (lane == 0) s1[u] = p * 0.125f;
    }
  }
  __syncthreads();
  if (t == 0) {
    for (int u = 0; u < 6; u++) {
      int cnt = 0;
      for (int u2 = 0; u2 < 6; u2++)
        if (s0[u2] > s0[u] || (s0[u2] == s0[u] && u2 < u)) cnt++;
      float mk = (cnt < 4) ? 1.0f : 0.0f;
      sm[u] = mk;
      maskf[(size_t)b * 6 + u] = mk;
      sp[u] = 1.0f / (1.0f + expf(s1[u] - s0[u]));
    }
  }
  __syncthreads();
  for (int idx = t; idx < 2400; idx += 256) {
    int u = idx / 400, j = idx % 400;
    float val = sm[u] * (sp[u] * bf2f(v_l0, (size_t)b * 400 + j) +
                         (1.0f - sp[u]) * ldin(bv, j, f));
    f2bf(inputs, ((size_t)b * 6 + u) * 400 + j, val);
  }
}

// ---------------- GRU elementwise ----------------
__global__ void rim_gru(const u16* __restrict__ Ggx, const u16* __restrict__ Ggh,
                        const void* __restrict__ hs, long R0,
                        u16* __restrict__ hy, long total,
                        const int* __restrict__ flagp)
{
  const int f = flagp[0];
  long idx = (long)blockIdx.x * 256 + threadIdx.x;
  if (idx >= total) return;
  long bu = idx >> 9;
  int h = idx & 511;
  size_t gb = (size_t)bu * 1536 + h;
  float xr = bf2f(Ggx, gb), xz = bf2f(Ggx, gb + 512), xn = bf2f(Ggx, gb + 1024);
  float hr = bf2f(Ggh, gb), hz = bf2f(Ggh, gb + 512), hn = bf2f(Ggh, gb + 1024);
  float r = 1.f / (1.f + expf(-(xr + hr)));
  float zz = 1.f / (1.f + expf(-(xz + hz)));
  float n = tanhf(xn + r * hn);
  float hv = ldin(hs, R0 + idx, f);
  f2bf(hy, idx, n + zz * (hv - n));
}

// ---------------- per-b attention: att -> softmax*mask -> ctx ----------------
__global__ __launch_bounds__(256)
void rim_attn(const u16* __restrict__ qk, const float* __restrict__ maskp,
              const u16* __restrict__ v, u16* __restrict__ ctx)
{
  int bl = blockIdx.x;
  int t = threadIdx.x;
  __shared__ float qs[1536];
  __shared__ float aps[144];
  __shared__ __align__(16) u16 vs[12288];
  for (int idx = t; idx < 1536; idx += 256)
    qs[idx] = bf2f(qk, (size_t)bl * 1536 + idx);
  for (int idx = t; idx < 1536; idx += 256)
    *reinterpret_cast<bf16x8*>(&vs[idx * 8]) =
        *reinterpret_cast<const bf16x8*>(
            reinterpret_cast<const __bf16*>(v) + (size_t)bl * 12288 + idx * 8);
  __syncthreads();
  if (t < 144) {
    int h = t / 36, r6 = t % 36, uq = r6 / 6, uk = r6 % 6;
    float s = 0.f;
#pragma unroll
    for (int d = 0; d < 32; d++)
      s += qs[uq * 256 + h * 32 + d] * qs[uk * 256 + 128 + h * 32 + d];
    aps[t] = s * 0.17677669529663687f;
  }
  __syncthreads();
  if (t < 24) {
    int h = t / 6, uq = t % 6;
    float* row = &aps[h * 36 + uq * 6];
    float mx = row[0];
    for (int k = 1; k < 6; k++) mx = fmaxf(mx, row[k]);
    float e[6], sum = 0.f;
    for (int k = 0; k < 6; k++) { e[k] = expf(row[k] - mx); sum += e[k]; }
    float mk = maskp[(size_t)bl * 6 + uq] / sum;
    for (int k = 0; k < 6; k++) row[k] = e[k] * mk;
  }
  __syncthreads();
  for (int idx = t; idx < 12288; idx += 256) {
    int uq = idx >> 11, g = idx & 2047, h = g >> 9;
    const float* ar = &aps[h * 36 + uq * 6];
    float acc = 0.f;
#pragma unroll
    for (int k = 0; k < 6; k++) acc += ar[k] * bf2f(vs, k * 2048 + g);
    f2bf(ctx, ((size_t)bl * 6 + uq) * 2048 + g, acc);
  }
}

// ---------------- host ----------------
extern "C" void kernel_launch(void* const* d_in, const int* in_sizes, int n_in,
                              void* d_out, int out_size, void* d_ws, size_t ws_size,
                              hipStream_t stream)
{
  (void)in_sizes; (void)n_in; (void)out_size;
  const void* x   = d_in[0];
  const void* hs  = d_in[1];
  const void* Wk  = d_in[2];
  const void* bk  = d_in[3];
  const void* Wv  = d_in[4];
  const void* bv  = d_in[5];
  const void* Wq  = d_in[6];
  const void* Wq_ = d_in[7];
  const void* Wk_ = d_in[8];
  const void* Wv_ = d_in[9];
  const void* Wo_ = d_in[10];
  const void* sw  = d_in[11];
  const void* gwx = d_in[12];
  const void* gwh = d_in[13];
  char* ws = (char*)d_ws;

  int*   flagp = (int*)(ws + OFF_FLAG);
  float* maskf = (float*)(ws + OFF_MASK);
  u16* WvT   = (u16*)(ws + OFF_WVT);
  u16* WqkT  = (u16*)(ws + OFF_WQKT);
  u16* WvT_  = (u16*)(ws + OFF_WVT_);
  u16* WoT   = (u16*)(ws + OFF_WOT);
  u16* WxcT  = (u16*)(ws + OFF_WXCT);
  u16* WhcT  = (u16*)(ws + OFF_WHCT);
  u16* hy    = (u16*)(ws + OFF_HY);
  u16* WKC   = (u16*)(ws + OFF_WKC);
  u16* WQC   = (u16*)(ws + OFF_WQC);
  u16* inputs = (u16*)(ws + A_INP);
  float* k_l0 = (float*)(ws + A_KL);
  float* q_l  = (float*)(ws + A_QL);
  u16* v_l0   = (u16*)(ws + A_VL);

  int R2 = 256, R3 = 256;
  {
    const int cand[5] = {4096, 2048, 1024, 512, 256};
    for (int i = 0; i < 5; i++)
      if (A_P1 + (size_t)cand[i] * 36864 <= ws_size) { R2 = cand[i]; break; }
    for (int i = 0; i < 5; i++)
      if (ARENA + (size_t)cand[i] * 52224 <= ws_size) { R3 = cand[i]; break; }
  }

  rim_detect<<<dim3(1), dim3(64), 0, stream>>>(sw, flagp);

  auto T = [&](const void* in, u16* outp, int N, int K, long iz, long oz, int Z) {
    dim3 g((K + 31) / 32, (N + 31) / 32, Z);
    rim_transpose<<<g, dim3(256), 0, stream>>>(in, outp, N, K, iz, oz, flagp);
  };
  T(Wv, WvT, 400, 1024, 0, 0, 1);
  T(Wq_, WqkT, 128, 512, 65536, 131072, 6);
  T(Wk_, WqkT + 65536, 128, 512, 65536, 131072, 6);
  T(Wv_, WvT_, 2048, 512, 1048576, 1048576, 6);
  T(Wo_, WoT, 512, 2048, 1048576, 1048576, 6);
  {
    long tk = 1L * 1024 * 64, tq = 6L * 512 * 64;
    rim_wcat<<<dim3((unsigned)((tk + 255) / 256)), dim3(256), 0, stream>>>(
        Wk, WKC, 64, 1024, 0, 0, tk, flagp);
    rim_wcat<<<dim3((unsigned)((tq + 255) / 256)), dim3(256), 0, stream>>>(
        Wq, WQC, 64, 512, 32768, 196608, tq, flagp);
    rim_gruw<<<dim3(25, 24, 6), dim3(256), 0, stream>>>(sw, gwx, WxcT, 400, flagp);
    rim_gruw<<<dim3(32, 24, 6), dim3(256), 0, stream>>>(sw, gwh, WhcT, 512, flagp);
  }

  auto G = [&](int epi, int adt, const void* A, long A0, long lda, long Az,
               const u16* B, long Bz, void* C, long C0, long ldc, long Cz,
               int M, int N, int K, int Z, int KP,
               const void* bias, const u16* hyp, const float* mp, const void* hsp) {
    dim3 g((M + 127) / 128, (N + 127) / 128, Z), blk(256);
    if (epi == 1 && adt == 2)
      rim_gemm<1, 2><<<g, blk, 0, stream>>>(A, A0, lda, Az, B, Bz, C, C0, ldc, Cz, M, N, K, KP, bias, hyp, mp, hsp, flagp);
    else if (epi == 0 && adt == 2)
      rim_gemm<0, 2><<<g, blk, 0, stream>>>(A, A0, lda, Az, B, Bz, C, C0, ldc, Cz, M, N, K, KP, bias, hyp, mp, hsp, flagp);
    else if (epi == 2 && adt == 1)
      rim_gemm<2, 1><<<g, blk, 0, stream>>>(A, A0, lda, Az, B, Bz, C, C0, ldc, Cz, M, N, K, KP, bias, hyp, mp, hsp, flagp);
    else if (epi == 3 && adt == 1)
      rim_gemm<3, 1><<<g, blk, 0, stream>>>(A, A0, lda, Az, B, Bz, C, C0, ldc, Cz, M, N, K, KP, bias, hyp, mp, hsp, flagp);
    else if (epi == 3 && adt == 0)
      rim_gemm<3, 0><<<g, blk, 0, stream>>>(A, A0, lda, Az, B, Bz, C, C0, ldc, Cz, M, N, K, KP, bias, hyp, mp, hsp, flagp);
    else
      rim_gemm<4, 0><<<g, blk, 0, stream>>>(A, A0, lda, Az, B, Bz, C, C0, ldc, Cz, M, N, K, KP, bias, hyp, mp, hsp, flagp);
  };

  // scores path: 3-way-split MFMA for k_l0 (K=6*1024) and q_l (K=6*512)
  G(1, 2, x, 0, 1024, 0, WKC, 0, k_l0, 0, 64, 0, 4096, 64, 6144, 1, 1024,
    bk, nullptr, nullptr, nullptr);
  G(0, 2, hs, 0, 3072, 512, WQC, 196608, q_l, 0, 384, 64, 4096, 64, 3072, 6, 512,
    nullptr, nullptr, nullptr, nullptr);
  G(2, 1, x, 0, 1024, 0, WvT, 0, v_l0, 0, 400, 0, 4096, 400, 1024, 1, 0,
    bv, nullptr, nullptr, nullptr);
  rim_scores<<<dim3(4096), dim3(256), 0, stream>>>(q_l, k_l0, bk, v_l0, bv,
                                                   maskf, inputs, flagp);

  // GRU in chunks of R2 rows
  u16* Ggx = (u16*)(ws + A_P1);
  u16* Ggh = (u16*)(ws + A_P1 + (size_t)R2 * 18432);
  for (int r0 = 0; r0 < 4096; r0 += R2) {
    G(3, 1, hs, (long)r0 * 3072, 3072, 512, WhcT, 786432, Ggh, 0, 9216, 1536,
      R2, 1536, 512, 6, 0, nullptr, nullptr, nullptr, nullptr);
    G(3, 0, inputs, (long)r0 * 2400, 2400, 400, WxcT, 614400, Ggx, 0, 9216, 1536,
      R2, 1536, 400, 6, 0, nullptr, nullptr, nullptr, nullptr);
    long total = (long)R2 * 3072;
    rim_gru<<<dim3((unsigned)(total / 256)), dim3(256), 0, stream>>>(
        Ggx, Ggh, hs, (long)r0 * 3072, hy + (size_t)r0 * 3072, total, flagp);
  }

  // attention + output in chunks of R3 rows
  u16* qk_c  = (u16*)(ws + ARENA);
  u16* v_c   = (u16*)(ws + ARENA + (size_t)R3 * 3072);
  u16* ctx_c = (u16*)(ws + ARENA + (size_t)R3 * 3072 + (size_t)R3 * 24576);
  for (int r0 = 0; r0 < 4096; r0 += R3) {
    G(3, 0, hy, (long)r0 * 3072, 3072, 512, WqkT, 131072, qk_c, 0, 1536, 256,
      R3, 256, 512, 6, 0, nullptr, nullptr, nullptr, nullptr);
    G(3, 0, hy, (long)r0 * 3072, 3072, 512, WvT_, 1048576, v_c, 0, 12288, 2048,
      R3, 2048, 512, 6, 0, nullptr, nullptr, nullptr, nullptr);
    rim_attn<<<dim3(R3), dim3(256), 0, stream>>>(qk_c, maskf + (size_t)r0 * 6, v_c, ctx_c);
    G(4, 0, ctx_c, 0, 12288, 2048, WoT, 1048576, d_out, (long)r0 * 3072, 3072, 512,
      R3, 512, 2048, 6, 0, nullptr, hy + (size_t)r0 * 3072, maskf + (size_t)r0 * 6, hs);
  }
}

// Round 4
// 1330.874 us; speedup vs baseline: 1.2199x; 1.2199x over previous
//
#include <hip/hip_runtime.h>
#include <cstddef>
#include <cstdint>

// RIMCell fused pipeline for MI355X (gfx950), dtype-robust (f32 or bf16 inputs).
// Scores path (top-k critical) uses dedicated f32 VALU tiled SGEMMs (exact
// products, 64x64 tiles) -- MFMA bf16 everywhere else.

typedef unsigned short u16;
typedef __bf16 bf16x8 __attribute__((ext_vector_type(8)));
typedef float f32x4 __attribute__((ext_vector_type(4)));
typedef u16 u16x4 __attribute__((ext_vector_type(4)));

#define DEVFN static __device__ __forceinline__

DEVFN float ldin(const void* p, size_t i, int f) {
  return f ? (float)reinterpret_cast<const __bf16*>(p)[i]
           : reinterpret_cast<const float*>(p)[i];
}
DEVFN float bf2f(const u16* p, size_t i) {
  return (float)reinterpret_cast<const __bf16*>(p)[i];
}
DEVFN void f2bf(u16* p, size_t i, float v) {
  reinterpret_cast<__bf16*>(p)[i] = (__bf16)v;
}
DEVFN u16 bfbits(float v) {
  __bf16 b = (__bf16)v;
  return *reinterpret_cast<u16*>(&b);
}

// ---------------- ws layout (bytes) ----------------
constexpr size_t OFF_FLAG = 0;
constexpr size_t OFF_MASK = 256;        // 4096*6*4 = 98304
constexpr size_t OFF_WVT  = 98560;      // 400*1024*2 = 819200
constexpr size_t OFF_WQKT = 917760;     // 6*256*512*2 = 1572864
constexpr size_t OFF_WVT_ = 2490624;    // 6*2048*512*2 = 12582912
constexpr size_t OFF_WOT  = 15073536;   // 6*512*2048*2 = 12582912
constexpr size_t OFF_WXCT = 27656448;   // 6*1536*400*2 = 7372800
constexpr size_t OFF_WHCT = 35029248;   // 6*1536*512*2 = 9437184
constexpr size_t OFF_HY   = 44466432;   // 4096*3072*2 = 25165824
constexpr size_t ARENA    = 72777984;
constexpr size_t A_INP    = ARENA;      // inputs bf16 4096*2400*2 = 19660800
constexpr size_t A_P1     = 92438784;
constexpr size_t A_KL     = A_P1;       // k_l0 f32 4096*64*4 = 1048576
constexpr size_t A_QL     = 93487360;   // q_l f32 4096*384*4 = 6291456
constexpr size_t A_VL     = 99778816;   // v_l0 bf16 4096*400*2 = 3276800
// P2 chunk: Ggx at A_P1, Ggh at A_P1 + R2*18432 (needs A_P1 + R2*36864)
// P3 chunk: qk at ARENA, v at +R3*3072, ctx at +R3*3072+R3*24576

// ---------------- dtype detection ----------------
__global__ void rim_detect(const void* sw, int* flagp) {
  if (threadIdx.x == 0) {
    float s = 0.f;
    for (int i = 0; i < 24; i++)
      s += (float)reinterpret_cast<const __bf16*>(sw)[i];
    flagp[0] = (s > 5.5f && s < 6.5f) ? 1 : 0;
  }
}

// ---------------- scores-path SGEMM: C[z][m][0:64] = A @ W (+bias), f32 ------
// A: A0 + m*lda + z*Az + k (dual dtype).  W: z*Wz + k*64 + n (dual dtype).
// C: m*ldc + z*Cz + n (f32).  M = gridDim.x*64, N = 64, K multiple of 32.
__global__ __launch_bounds__(256)
void rim_sgemm(const void* __restrict__ A_, long lda, long Az,
               const void* __restrict__ W_, long Wz,
               float* __restrict__ C_, long ldc, long Cz,
               int K, const void* __restrict__ bias,
               const int* __restrict__ flagp)
{
  const int f = flagp[0];
  __shared__ float As[64 * 33];
  __shared__ float Ws[32 * 68];
  const int t = threadIdx.x;
  const int m0 = blockIdx.x * 64, z = blockIdx.z;
  const int tx = t & 15, ty = t >> 4;  // cols tx*4, rows ty*4

  f32x4 acc[4];
#pragma unroll
  for (int i = 0; i < 4; i++)
#pragma unroll
    for (int j = 0; j < 4; j++) acc[i][j] = 0.f;

  for (int k0 = 0; k0 < K; k0 += 32) {
#pragma unroll
    for (int j = 0; j < 8; j++) {
      int idx = t + j * 256;
      int row = idx >> 5, kk = idx & 31;
      As[row * 33 + kk] =
          ldin(A_, (size_t)(m0 + row) * lda + (size_t)z * Az + k0 + kk, f);
    }
#pragma unroll
    for (int j = 0; j < 8; j++) {
      int idx = t + j * 256;
      int kk = idx >> 6, n = idx & 63;
      Ws[kk * 68 + n] = ldin(W_, (size_t)z * Wz + (size_t)(k0 + kk) * 64 + n, f);
    }
    __syncthreads();
#pragma unroll 8
    for (int kk = 0; kk < 32; kk++) {
      f32x4 wv = *reinterpret_cast<const f32x4*>(&Ws[kk * 68 + tx * 4]);
#pragma unroll
      for (int i = 0; i < 4; i++) {
        float a = As[(ty * 4 + i) * 33 + kk];
#pragma unroll
        for (int j = 0; j < 4; j++) acc[i][j] += a * wv[j];
      }
    }
    __syncthreads();
  }
#pragma unroll
  for (int i = 0; i < 4; i++) {
    f32x4 o = acc[i];
    if (bias) {
#pragma unroll
      for (int j = 0; j < 4; j++) o[j] += ldin(bias, tx * 4 + j, f);
    }
    *reinterpret_cast<f32x4*>(
        &C_[(size_t)(m0 + ty * 4 + i) * ldc + (size_t)z * Cz + tx * 4]) = o;
  }
}

// ---------------- GEMM: C = A @ Bt^T, 128x128 tile, mfma 16x16x32 bf16 -------
// ADT: 0 ws bf16, 1 original input (dual dtype).
// EPI: 2 bf16+bias(orig), 3 bf16, 4 final select.
constexpr int LP = 40;  // LDS row stride (bf16 elems): 80 B, 16B-aligned, 2-way banks
template<int EPI, int ADT>
__global__ __launch_bounds__(256)
void rim_gemm(const void* __restrict__ A_, long A0, long lda, long Az,
              const u16* __restrict__ B_, long Bz,
              void* __restrict__ C_, long C0, long ldc, long Cz,
              int M, int N, int K,
              const void* __restrict__ bias,
              const u16* __restrict__ hyp,
              const float* __restrict__ maskp,
              const void* __restrict__ hsp,
              const int* __restrict__ flagp)
{
  __shared__ __align__(16) __bf16 As[128 * LP];
  __shared__ __align__(16) __bf16 Bs[128 * LP];
  const int f = flagp[0];
  const int t = threadIdx.x;
  const int m0 = blockIdx.x * 128, n0 = blockIdx.y * 128, z = blockIdx.z;
  const __bf16* Bb = reinterpret_cast<const __bf16*>(B_) + (size_t)z * Bz;
  const int lane = t & 63, w = t >> 6;
  const int wm = (w & 1) * 64, wn = (w >> 1) * 64;
  const int lr = lane & 15, lk = (lane >> 4) * 8;

  f32x4 acc[4][4];
#pragma unroll
  for (int i = 0; i < 4; i++)
#pragma unroll
    for (int j = 0; j < 4; j++)
#pragma unroll
      for (int r = 0; r < 4; r++) acc[i][j][r] = 0.f;

  const int r0 = t >> 2;
  const int kc0 = (t & 3) << 3;

  for (int k0 = 0; k0 < K; k0 += 32) {
#pragma unroll
    for (int it = 0; it < 2; it++) {
      int row = r0 + it * 64;
      int gk = k0 + kc0;
      bf16x8 av, bv8;
#pragma unroll
      for (int q = 0; q < 8; q++) { av[q] = (__bf16)0.f; bv8[q] = (__bf16)0.f; }
      int gm = m0 + row;
      if (gm < M && gk < K) {
        if constexpr (ADT == 0) {
          av = *reinterpret_cast<const bf16x8*>(
              reinterpret_cast<const __bf16*>(A_) + (size_t)A0 + (size_t)z * Az +
              (size_t)gm * lda + gk);
        } else {
          size_t idx = (size_t)A0 + (size_t)z * Az + (size_t)gm * lda + gk;
          if (f) {
            av = *reinterpret_cast<const bf16x8*>(
                reinterpret_cast<const __bf16*>(A_) + idx);
          } else {
            const f32x4* fp = reinterpret_cast<const f32x4*>(
                reinterpret_cast<const float*>(A_) + idx);
            f32x4 lo = fp[0], hi = fp[1];
#pragma unroll
            for (int q = 0; q < 4; q++) {
              av[q] = (__bf16)lo[q]; av[q + 4] = (__bf16)hi[q];
            }
          }
        }
      }
      int gn = n0 + row;
      if (gn < N && gk < K)
        bv8 = *reinterpret_cast<const bf16x8*>(Bb + (size_t)gn * (size_t)K + gk);
      *reinterpret_cast<bf16x8*>(&As[row * LP + kc0]) = av;
      *reinterpret_cast<bf16x8*>(&Bs[row * LP + kc0]) = bv8;
    }
    __syncthreads();
    bf16x8 af[4], bg[4];
#pragma unroll
    for (int i = 0; i < 4; i++)
      af[i] = *reinterpret_cast<const bf16x8*>(&As[(wm + i * 16 + lr) * LP + lk]);
#pragma unroll
    for (int j = 0; j < 4; j++)
      bg[j] = *reinterpret_cast<const bf16x8*>(&Bs[(wn + j * 16 + lr) * LP + lk]);
#pragma unroll
    for (int i = 0; i < 4; i++)
#pragma unroll
      for (int j = 0; j < 4; j++)
        acc[i][j] = __builtin_amdgcn_mfma_f32_16x16x32_bf16(af[i], bg[j], acc[i][j], 0, 0, 0);
    __syncthreads();
  }

  const int rq = (lane >> 4) * 4;  // C/D: row=(lane>>4)*4+reg, col=lane&15
  const int cq = lane & 15;
#pragma unroll
  for (int i = 0; i < 4; i++) {
#pragma unroll
    for (int j = 0; j < 4; j++) {
      int cg = n0 + wn + j * 16 + cq;
      if (cg >= N) continue;
#pragma unroll
      for (int r = 0; r < 4; r++) {
        int rg = m0 + wm + i * 16 + rq + r;
        if (rg >= M) continue;
        float v = acc[i][j][r];
        size_t cidx = (size_t)rg * ldc + (size_t)z * Cz + cg;
        if constexpr (EPI == 2) {
          f2bf((u16*)C_, C0 + cidx, v + ldin(bias, cg, f));
        } else if constexpr (EPI == 3) {
          f2bf((u16*)C_, C0 + cidx, v);
        } else {
          float mk = maskp[(size_t)rg * 6 + z];
          if (mk > 0.5f) {
            float o = v + bf2f(hyp, cidx);
            if (f) f2bf((u16*)C_, C0 + cidx, o);
            else   reinterpret_cast<float*>(C_)[C0 + cidx] = o;
          } else {
            if (f) reinterpret_cast<u16*>(C_)[C0 + cidx] =
                       reinterpret_cast<const u16*>(hsp)[C0 + cidx];
            else   reinterpret_cast<float*>(C_)[C0 + cidx] =
                       reinterpret_cast<const float*>(hsp)[C0 + cidx];
          }
        }
      }
    }
  }
}

// ------- tiled transpose to bf16: out[z][n][k] = cvt(in[z][k][n]) -----------
__global__ __launch_bounds__(256)
void rim_transpose(const void* __restrict__ in, u16* __restrict__ out,
                   int N, int K, long in_z, long out_z,
                   const int* __restrict__ flagp)
{
  const int f = flagp[0];
  __shared__ float tile[32][33];
  int z = blockIdx.z;
  int k0 = blockIdx.x * 32, n0 = blockIdx.y * 32;
  int c = threadIdx.x & 31, r = threadIdx.x >> 5;
  for (int rr = r; rr < 32; rr += 8) {
    int k = k0 + rr, n = n0 + c;
    tile[rr][c] = (k < K && n < N)
        ? ldin(in, (size_t)z * in_z + (size_t)k * N + n, f) : 0.f;
  }
  __syncthreads();
  for (int rr = r; rr < 32; rr += 8) {
    int n = n0 + rr, k = k0 + c;
    if (n < N && k < K)
      f2bf(out, (size_t)z * out_z + (size_t)n * K + k, tile[c][rr]);
  }
}

// ------- combined GRU weight, tiled transpose: out[u][o][i]=sum_s sw*gw[s][i][o]
__global__ __launch_bounds__(256)
void rim_gruw(const void* __restrict__ sw, const void* __restrict__ gw,
              u16* __restrict__ out, int IVH, const int* __restrict__ flagp)
{
  const int f = flagp[0];
  __shared__ float lds[64 * 17];
  int u = blockIdx.z;
  int i0 = blockIdx.x * 16, o0 = blockIdx.y * 64;
  int t = threadIdx.x;
  float s0 = ldin(sw, u * 4 + 0, f), s1 = ldin(sw, u * 4 + 1, f);
  float s2 = ldin(sw, u * 4 + 2, f), s3 = ldin(sw, u * 4 + 3, f);
  int oo = t & 63, iq = t >> 6;
  size_t pl = (size_t)IVH * 1536;
#pragma unroll
  for (int r = 0; r < 4; r++) {
    int ii = iq * 4 + r;
    size_t base = (size_t)(i0 + ii) * 1536 + o0 + oo;
    float acc = s0 * ldin(gw, base, f) + s1 * ldin(gw, pl + base, f) +
                s2 * ldin(gw, 2 * pl + base, f) + s3 * ldin(gw, 3 * pl + base, f);
    lds[oo * 17 + ii] = acc;
  }
  __syncthreads();
  int ow = t >> 2, iw = (t & 3) * 4;
  u16x4 pk;
#pragma unroll
  for (int j = 0; j < 4; j++) pk[j] = bfbits(lds[ow * 17 + iw + j]);
  *reinterpret_cast<u16x4*>(out + ((size_t)u * 1536 + o0 + ow) * IVH + i0 + iw) = pk;
}

// ---------------- scores / top-4 mask / 2-way softmax / inputs ----------------
__global__ __launch_bounds__(256)
void rim_scores(const float* __restrict__ q_l, const float* __restrict__ k_l0,
                const void* __restrict__ bk, const u16* __restrict__ v_l0,
                const void* __restrict__ bv, float* __restrict__ maskf,
                u16* __restrict__ inputs, const int* __restrict__ flagp)
{
  const int f = flagp[0];
  int b = blockIdx.x;
  int t = threadIdx.x;
  int lane = t & 63;
  __shared__ float s0[6], s1[6], sm[6], sp[6];
  if (t < 64) {
    float kv = k_l0[(size_t)b * 64 + lane];
    for (int u = 0; u < 6; u++) {
      float p = q_l[((size_t)b * 6 + u) * 64 + lane] * kv;
      for (int off = 32; off; off >>= 1) p += __shfl_down(p, off);
      if (lane == 0) s0[u] = p * 0.125f;
    }
  } else if (t < 128) {
    float kv = ldin(bk, lane, f);
    for (int u = 0; u < 6; u++) {
      float p = q_l[((size_t)b * 6 + u) * 64 + lane] * kv;
      for (int off = 32; off; off >>= 1) p += __shfl_down(p, off);
      if (lane == 0) s1[u] = p * 0.125f;
    }
  }
  __syncthreads();
  if (t == 0) {
    for (int u = 0; u < 6; u++) {
      int cnt = 0;
      for (int u2 = 0; u2 < 6; u2++)
        if (s0[u2] > s0[u] || (s0[u2] == s0[u] && u2 < u)) cnt++;
      float mk = (cnt < 4) ? 1.0f : 0.0f;
      sm[u] = mk;
      maskf[(size_t)b * 6 + u] = mk;
      sp[u] = 1.0f / (1.0f + expf(s1[u] - s0[u]));
    }
  }
  __syncthreads();
  for (int idx = t; idx < 2400; idx += 256) {
    int u = idx / 400, j = idx % 400;
    float val = sm[u] * (sp[u] * bf2f(v_l0, (size_t)b * 400 + j) +
                         (1.0f - sp[u]) * ldin(bv, j, f));
    f2bf(inputs, ((size_t)b * 6 + u) * 400 + j, val);
  }
}

// ---------------- GRU elementwise ----------------
__global__ void rim_gru(const u16* __restrict__ Ggx, const u16* __restrict__ Ggh,
                        const void* __restrict__ hs, long R0,
                        u16* __restrict__ hy, long total,
                        const int* __restrict__ flagp)
{
  const int f = flagp[0];
  long idx = (long)blockIdx.x * 256 + threadIdx.x;
  if (idx >= total) return;
  long bu = idx >> 9;
  int h = idx & 511;
  size_t gb = (size_t)bu * 1536 + h;
  float xr = bf2f(Ggx, gb), xz = bf2f(Ggx, gb + 512), xn = bf2f(Ggx, gb + 1024);
  float hr = bf2f(Ggh, gb), hz = bf2f(Ggh, gb + 512), hn = bf2f(Ggh, gb + 1024);
  float r = 1.f / (1.f + expf(-(xr + hr)));
  float zz = 1.f / (1.f + expf(-(xz + hz)));
  float n = tanhf(xn + r * hn);
  float hv = ldin(hs, R0 + idx, f);
  f2bf(hy, idx, n + zz * (hv - n));
}

// ---------------- per-b attention: att -> softmax*mask -> ctx ----------------
__global__ __launch_bounds__(256)
void rim_attn(const u16* __restrict__ qk, const float* __restrict__ maskp,
              const u16* __restrict__ v, u16* __restrict__ ctx)
{
  int bl = blockIdx.x;
  int t = threadIdx.x;
  __shared__ float qs[1536];
  __shared__ float aps[144];
  __shared__ __align__(16) u16 vs[12288];
  for (int idx = t; idx < 1536; idx += 256)
    qs[idx] = bf2f(qk, (size_t)bl * 1536 + idx);
  for (int idx = t; idx < 1536; idx += 256)
    *reinterpret_cast<bf16x8*>(&vs[idx * 8]) =
        *reinterpret_cast<const bf16x8*>(
            reinterpret_cast<const __bf16*>(v) + (size_t)bl * 12288 + idx * 8);
  __syncthreads();
  if (t < 144) {
    int h = t / 36, r6 = t % 36, uq = r6 / 6, uk = r6 % 6;
    float s = 0.f;
#pragma unroll
    for (int d = 0; d < 32; d++)
      s += qs[uq * 256 + h * 32 + d] * qs[uk * 256 + 128 + h * 32 + d];
    aps[t] = s * 0.17677669529663687f;
  }
  __syncthreads();
  if (t < 24) {
    int h = t / 6, uq = t % 6;
    float* row = &aps[h * 36 + uq * 6];
    float mx = row[0];
    for (int k = 1; k < 6; k++) mx = fmaxf(mx, row[k]);
    float e[6], sum = 0.f;
    for (int k = 0; k < 6; k++) { e[k] = expf(row[k] - mx); sum += e[k]; }
    float mk = maskp[(size_t)bl * 6 + uq] / sum;
    for (int k = 0; k < 6; k++) row[k] = e[k] * mk;
  }
  __syncthreads();
  for (int idx = t; idx < 12288; idx += 256) {
    int uq = idx >> 11, g = idx & 2047, h = g >> 9;
    const float* ar = &aps[h * 36 + uq * 6];
    float acc = 0.f;
#pragma unroll
    for (int k = 0; k < 6; k++) acc += ar[k] * bf2f(vs, k * 2048 + g);
    f2bf(ctx, ((size_t)bl * 6 + uq) * 2048 + g, acc);
  }
}

// ---------------- host ----------------
extern "C" void kernel_launch(void* const* d_in, const int* in_sizes, int n_in,
                              void* d_out, int out_size, void* d_ws, size_t ws_size,
                              hipStream_t stream)
{
  (void)in_sizes; (void)n_in; (void)out_size;
  const void* x   = d_in[0];
  const void* hs  = d_in[1];
  const void* Wk  = d_in[2];
  const void* bk  = d_in[3];
  const void* Wv  = d_in[4];
  const void* bv  = d_in[5];
  const void* Wq  = d_in[6];
  const void* Wq_ = d_in[7];
  const void* Wk_ = d_in[8];
  const void* Wv_ = d_in[9];
  const void* Wo_ = d_in[10];
  const void* sw  = d_in[11];
  const void* gwx = d_in[12];
  const void* gwh = d_in[13];
  char* ws = (char*)d_ws;

  int*   flagp = (int*)(ws + OFF_FLAG);
  float* maskf = (float*)(ws + OFF_MASK);
  u16* WvT   = (u16*)(ws + OFF_WVT);
  u16* WqkT  = (u16*)(ws + OFF_WQKT);
  u16* WvT_  = (u16*)(ws + OFF_WVT_);
  u16* WoT   = (u16*)(ws + OFF_WOT);
  u16* WxcT  = (u16*)(ws + OFF_WXCT);
  u16* WhcT  = (u16*)(ws + OFF_WHCT);
  u16* hy    = (u16*)(ws + OFF_HY);
  u16* inputs = (u16*)(ws + A_INP);
  float* k_l0 = (float*)(ws + A_KL);
  float* q_l  = (float*)(ws + A_QL);
  u16* v_l0   = (u16*)(ws + A_VL);

  int R2 = 256, R3 = 256;
  {
    const int cand[5] = {4096, 2048, 1024, 512, 256};
    for (int i = 0; i < 5; i++)
      if (A_P1 + (size_t)cand[i] * 36864 <= ws_size) { R2 = cand[i]; break; }
    for (int i = 0; i < 5; i++)
      if (ARENA + (size_t)cand[i] * 52224 <= ws_size) { R3 = cand[i]; break; }
  }

  rim_detect<<<dim3(1), dim3(64), 0, stream>>>(sw, flagp);

  auto T = [&](const void* in, u16* outp, int N, int K, long iz, long oz, int Z) {
    dim3 g((K + 31) / 32, (N + 31) / 32, Z);
    rim_transpose<<<g, dim3(256), 0, stream>>>(in, outp, N, K, iz, oz, flagp);
  };
  T(Wv, WvT, 400, 1024, 0, 0, 1);
  T(Wq_, WqkT, 128, 512, 65536, 131072, 6);
  T(Wk_, WqkT + 65536, 128, 512, 65536, 131072, 6);
  T(Wv_, WvT_, 2048, 512, 1048576, 1048576, 6);
  T(Wo_, WoT, 512, 2048, 1048576, 1048576, 6);
  rim_gruw<<<dim3(25, 24, 6), dim3(256), 0, stream>>>(sw, gwx, WxcT, 400, flagp);
  rim_gruw<<<dim3(32, 24, 6), dim3(256), 0, stream>>>(sw, gwh, WhcT, 512, flagp);

  auto G = [&](int epi, int adt, const void* A, long A0, long lda, long Az,
               const u16* B, long Bz, void* C, long C0, long ldc, long Cz,
               int M, int N, int K, int Z,
               const void* bias, const u16* hyp, const float* mp, const void* hsp) {
    dim3 g((M + 127) / 128, (N + 127) / 128, Z), blk(256);
    if (epi == 2 && adt == 1)
      rim_gemm<2, 1><<<g, blk, 0, stream>>>(A, A0, lda, Az, B, Bz, C, C0, ldc, Cz, M, N, K, bias, hyp, mp, hsp, flagp);
    else if (epi == 3 && adt == 1)
      rim_gemm<3, 1><<<g, blk, 0, stream>>>(A, A0, lda, Az, B, Bz, C, C0, ldc, Cz, M, N, K, bias, hyp, mp, hsp, flagp);
    else if (epi == 3 && adt == 0)
      rim_gemm<3, 0><<<g, blk, 0, stream>>>(A, A0, lda, Az, B, Bz, C, C0, ldc, Cz, M, N, K, bias, hyp, mp, hsp, flagp);
    else
      rim_gemm<4, 0><<<g, blk, 0, stream>>>(A, A0, lda, Az, B, Bz, C, C0, ldc, Cz, M, N, K, bias, hyp, mp, hsp, flagp);
  };

  // scores path: dedicated f32 VALU SGEMMs (exact products -> stable top-k)
  rim_sgemm<<<dim3(64, 1, 1), dim3(256), 0, stream>>>(
      x, 1024, 0, Wk, 0, k_l0, 64, 0, 1024, bk, flagp);
  rim_sgemm<<<dim3(64, 1, 6), dim3(256), 0, stream>>>(
      hs, 3072, 512, Wq, 32768, q_l, 384, 64, 512, nullptr, flagp);
  G(2, 1, x, 0, 1024, 0, WvT, 0, v_l0, 0, 400, 0, 4096, 400, 1024, 1,
    bv, nullptr, nullptr, nullptr);
  rim_scores<<<dim3(4096), dim3(256), 0, stream>>>(q_l, k_l0, bk, v_l0, bv,
                                                   maskf, inputs, flagp);

  // GRU in chunks of R2 rows
  u16* Ggx = (u16*)(ws + A_P1);
  u16* Ggh = (u16*)(ws + A_P1 + (size_t)R2 * 18432);
  for (int r0 = 0; r0 < 4096; r0 += R2) {
    G(3, 1, hs, (long)r0 * 3072, 3072, 512, WhcT, 786432, Ggh, 0, 9216, 1536,
      R2, 1536, 512, 6, nullptr, nullptr, nullptr, nullptr);
    G(3, 0, inputs, (long)r0 * 2400, 2400, 400, WxcT, 614400, Ggx, 0, 9216, 1536,
      R2, 1536, 400, 6, nullptr, nullptr, nullptr, nullptr);
    long total = (long)R2 * 3072;
    rim_gru<<<dim3((unsigned)(total / 256)), dim3(256), 0, stream>>>(
        Ggx, Ggh, hs, (long)r0 * 3072, hy + (size_t)r0 * 3072, total, flagp);
  }

  // attention + output in chunks of R3 rows
  u16* qk_c  = (u16*)(ws + ARENA);
  u16* v_c   = (u16*)(ws + ARENA + (size_t)R3 * 3072);
  u16* ctx_c = (u16*)(ws + ARENA + (size_t)R3 * 3072 + (size_t)R3 * 24576);
  for (int r0 = 0; r0 < 4096; r0 += R3) {
    G(3, 0, hy, (long)r0 * 3072, 3072, 512, WqkT, 131072, qk_c, 0, 1536, 256,
      R3, 256, 512, 6, nullptr, nullptr, nullptr, nullptr);
    G(3, 0, hy, (long)r0 * 3072, 3072, 512, WvT_, 1048576, v_c, 0, 12288, 2048,
      R3, 2048, 512, 6, nullptr, nullptr, nullptr, nullptr);
    rim_attn<<<dim3(R3), dim3(256), 0, stream>>>(qk_c, maskf + (size_t)r0 * 6, v_c, ctx_c);
    G(4, 0, ctx_c, 0, 12288, 2048, WoT, 1048576, d_out, (long)r0 * 3072, 3072, 512,
      R3, 512, 2048, 6, nullptr, hy + (size_t)r0 * 3072, maskf + (size_t)r0 * 6, hs);
  }
}

// Round 5
// 1067.195 us; speedup vs baseline: 1.5213x; 1.2471x over previous
//
#include <hip/hip_runtime.h>
#include <cstddef>
#include <cstdint>

// RIMCell fused pipeline for MI355X (gfx950), dtype-robust (f32 or bf16 inputs).
// Scores path (top-k critical): f32 VALU split-K SGEMM (exact products,
// deterministic two-pass reduce). MFMA bf16 everywhere else.

typedef unsigned short u16;
typedef __bf16 bf16x8 __attribute__((ext_vector_type(8)));
typedef float f32x4 __attribute__((ext_vector_type(4)));
typedef u16 u16x4 __attribute__((ext_vector_type(4)));

#define DEVFN static __device__ __forceinline__

DEVFN float ldin(const void* p, size_t i, int f) {
  return f ? (float)reinterpret_cast<const __bf16*>(p)[i]
           : reinterpret_cast<const float*>(p)[i];
}
DEVFN float bf2f(const u16* p, size_t i) {
  return (float)reinterpret_cast<const __bf16*>(p)[i];
}
DEVFN void f2bf(u16* p, size_t i, float v) {
  reinterpret_cast<__bf16*>(p)[i] = (__bf16)v;
}
DEVFN u16 bfbits(float v) {
  __bf16 b = (__bf16)v;
  return *reinterpret_cast<u16*>(&b);
}

// ---------------- ws layout (bytes) ----------------
constexpr size_t OFF_FLAG = 0;
constexpr size_t OFF_MASK = 256;        // 4096*6*4 = 98304
constexpr size_t OFF_WVT  = 98560;      // 400*1024*2 = 819200
constexpr size_t OFF_WQKT = 917760;     // 6*256*512*2 = 1572864
constexpr size_t OFF_WVT_ = 2490624;    // 6*2048*512*2 = 12582912
constexpr size_t OFF_WOT  = 15073536;   // 6*512*2048*2 = 12582912
constexpr size_t OFF_WXCT = 27656448;   // 6*1536*400*2 = 7372800
constexpr size_t OFF_WHCT = 35029248;   // 6*1536*512*2 = 9437184
constexpr size_t OFF_HY   = 44466432;   // 4096*3072*2 = 25165824
constexpr size_t ARENA    = 72777984;
constexpr size_t A_INP    = ARENA;      // inputs bf16 4096*2400*2 = 19660800
// scores partials overlay A_INP (dead until rim_scores writes inputs):
constexpr size_t A_PK     = ARENA;              // 4*4096*64*4   = 4194304
constexpr size_t A_PQ     = ARENA + 4194304;    // 2*6*4096*64*4 = 12582912
constexpr size_t A_P1     = 92438784;
constexpr size_t A_KL     = A_P1;       // k_l0 f32 4096*64*4 = 1048576
constexpr size_t A_QL     = 93487360;   // q_l f32 4096*384*4 = 6291456
constexpr size_t A_VL     = 99778816;   // v_l0 bf16 4096*400*2 = 3276800
// P2 chunk: Ggx at A_P1, Ggh at A_P1 + R2*18432 (needs A_P1 + R2*36864)
// P3 chunk: qk at ARENA, v at +R3*3072, ctx at +R3*3072+R3*24576

// ---------------- dtype detection ----------------
__global__ void rim_detect(const void* sw, int* flagp) {
  if (threadIdx.x == 0) {
    float s = 0.f;
    for (int i = 0; i < 24; i++)
      s += (float)reinterpret_cast<const __bf16*>(sw)[i];
    flagp[0] = (s > 5.5f && s < 6.5f) ? 1 : 0;
  }
}

// -------- scores-path split-K SGEMM: P[kc][z][m0+32)[64] partials, f32 -------
// A: m*lda + z*Az + k (dual dtype). W: z*Wz + k*64 + n (dual dtype).
// grid: (M/32, NK, Z); each block does 32 rows x 64 cols x KC k's.
__global__ __launch_bounds__(256)
void rim_sgemm32(const void* __restrict__ A_, long lda, long Az,
                 const void* __restrict__ W_, long Wz,
                 float* __restrict__ P, int KC,
                 const int* __restrict__ flagp)
{
  const int f = flagp[0];
  __shared__ float As[32 * 33];
  __shared__ float Ws[32 * 68];
  const int t = threadIdx.x;
  const int m0 = blockIdx.x * 32, kc = blockIdx.y, z = blockIdx.z;
  const int Z = gridDim.z;
  const int kb = kc * KC;
  const int tx = t & 15, ty = t >> 4;  // cols tx*4..+3, rows ty*2..+1

  f32x4 acc[2];
#pragma unroll
  for (int i = 0; i < 2; i++)
#pragma unroll
    for (int j = 0; j < 4; j++) acc[i][j] = 0.f;

  for (int k0 = kb; k0 < kb + KC; k0 += 32) {
#pragma unroll
    for (int j = 0; j < 4; j++) {
      int idx = t + j * 256;
      int row = idx >> 5, kk = idx & 31;
      As[row * 33 + kk] =
          ldin(A_, (size_t)(m0 + row) * lda + (size_t)z * Az + k0 + kk, f);
    }
#pragma unroll
    for (int j = 0; j < 8; j++) {
      int idx = t + j * 256;
      int kk = idx >> 6, n = idx & 63;
      Ws[kk * 68 + n] = ldin(W_, (size_t)z * Wz + (size_t)(k0 + kk) * 64 + n, f);
    }
    __syncthreads();
#pragma unroll 8
    for (int kk = 0; kk < 32; kk++) {
      f32x4 wv = *reinterpret_cast<const f32x4*>(&Ws[kk * 68 + tx * 4]);
#pragma unroll
      for (int i = 0; i < 2; i++) {
        float a = As[(ty * 2 + i) * 33 + kk];
#pragma unroll
        for (int j = 0; j < 4; j++) acc[i][j] += a * wv[j];
      }
    }
    __syncthreads();
  }
  float* Pb = P + ((size_t)kc * Z + z) * (4096 * 64);
#pragma unroll
  for (int i = 0; i < 2; i++)
    *reinterpret_cast<f32x4*>(&Pb[(size_t)(m0 + ty * 2 + i) * 64 + tx * 4]) = acc[i];
}

// -------- reduce partials: C[m*ldc + z*Cz + n] = bias[n] + sum_kc P ---------
__global__ void rim_sreduce(const float* __restrict__ P, int NK, int Z,
                            float* __restrict__ C, long ldc, long Cz,
                            const void* __restrict__ bias,
                            const int* __restrict__ flagp, long total)
{
  const int f = flagp[0];
  long idx = (long)blockIdx.x * 256 + threadIdx.x;
  if (idx >= total) return;
  long z = idx / (4096 * 64);
  long r = idx - z * (4096 * 64);
  long m = r >> 6;
  int n = (int)(r & 63);
  float s = bias ? ldin(bias, n, f) : 0.f;
  for (int kc = 0; kc < NK; kc++)
    s += P[((size_t)kc * Z + z) * (4096 * 64) + r];
  C[(size_t)m * ldc + (size_t)z * Cz + n] = s;
}

// ---------------- GEMM: C = A @ Bt^T, 128x128 tile, mfma 16x16x32 bf16 -------
// ADT: 0 ws bf16, 1 original input (dual dtype).
// EPI: 2 bf16+bias(orig), 3 bf16, 4 final select.
constexpr int LP = 40;  // LDS row stride (bf16): 80 B, 16B-aligned, 2-way banks
template<int EPI, int ADT>
__global__ __launch_bounds__(256)
void rim_gemm(const void* __restrict__ A_, long A0, long lda, long Az,
              const u16* __restrict__ B_, long Bz,
              void* __restrict__ C_, long C0, long ldc, long Cz,
              int M, int N, int K,
              const void* __restrict__ bias,
              const u16* __restrict__ hyp,
              const float* __restrict__ maskp,
              const void* __restrict__ hsp,
              const int* __restrict__ flagp)
{
  __shared__ __align__(16) __bf16 As[128 * LP];
  __shared__ __align__(16) __bf16 Bs[128 * LP];
  const int f = flagp[0];
  const int t = threadIdx.x;
  const int m0 = blockIdx.x * 128, n0 = blockIdx.y * 128, z = blockIdx.z;
  const __bf16* Bb = reinterpret_cast<const __bf16*>(B_) + (size_t)z * Bz;
  const int lane = t & 63, w = t >> 6;
  const int wm = (w & 1) * 64, wn = (w >> 1) * 64;
  const int lr = lane & 15, lk = (lane >> 4) * 8;

  f32x4 acc[4][4];
#pragma unroll
  for (int i = 0; i < 4; i++)
#pragma unroll
    for (int j = 0; j < 4; j++)
#pragma unroll
      for (int r = 0; r < 4; r++) acc[i][j][r] = 0.f;

  const int r0 = t >> 2;
  const int kc0 = (t & 3) << 3;

  for (int k0 = 0; k0 < K; k0 += 32) {
#pragma unroll
    for (int it = 0; it < 2; it++) {
      int row = r0 + it * 64;
      int gk = k0 + kc0;
      bf16x8 av, bv8;
#pragma unroll
      for (int q = 0; q < 8; q++) { av[q] = (__bf16)0.f; bv8[q] = (__bf16)0.f; }
      int gm = m0 + row;
      if (gm < M && gk < K) {
        if constexpr (ADT == 0) {
          av = *reinterpret_cast<const bf16x8*>(
              reinterpret_cast<const __bf16*>(A_) + (size_t)A0 + (size_t)z * Az +
              (size_t)gm * lda + gk);
        } else {
          size_t idx = (size_t)A0 + (size_t)z * Az + (size_t)gm * lda + gk;
          if (f) {
            av = *reinterpret_cast<const bf16x8*>(
                reinterpret_cast<const __bf16*>(A_) + idx);
          } else {
            const f32x4* fp = reinterpret_cast<const f32x4*>(
                reinterpret_cast<const float*>(A_) + idx);
            f32x4 lo = fp[0], hi = fp[1];
#pragma unroll
            for (int q = 0; q < 4; q++) {
              av[q] = (__bf16)lo[q]; av[q + 4] = (__bf16)hi[q];
            }
          }
        }
      }
      int gn = n0 + row;
      if (gn < N && gk < K)
        bv8 = *reinterpret_cast<const bf16x8*>(Bb + (size_t)gn * (size_t)K + gk);
      *reinterpret_cast<bf16x8*>(&As[row * LP + kc0]) = av;
      *reinterpret_cast<bf16x8*>(&Bs[row * LP + kc0]) = bv8;
    }
    __syncthreads();
    bf16x8 af[4], bg[4];
#pragma unroll
    for (int i = 0; i < 4; i++)
      af[i] = *reinterpret_cast<const bf16x8*>(&As[(wm + i * 16 + lr) * LP + lk]);
#pragma unroll
    for (int j = 0; j < 4; j++)
      bg[j] = *reinterpret_cast<const bf16x8*>(&Bs[(wn + j * 16 + lr) * LP + lk]);
#pragma unroll
    for (int i = 0; i < 4; i++)
#pragma unroll
      for (int j = 0; j < 4; j++)
        acc[i][j] = __builtin_amdgcn_mfma_f32_16x16x32_bf16(af[i], bg[j], acc[i][j], 0, 0, 0);
    __syncthreads();
  }

  const int rq = (lane >> 4) * 4;  // C/D: row=(lane>>4)*4+reg, col=lane&15
  const int cq = lane & 15;
#pragma unroll
  for (int i = 0; i < 4; i++) {
#pragma unroll
    for (int j = 0; j < 4; j++) {
      int cg = n0 + wn + j * 16 + cq;
      if (cg >= N) continue;
#pragma unroll
      for (int r = 0; r < 4; r++) {
        int rg = m0 + wm + i * 16 + rq + r;
        if (rg >= M) continue;
        float v = acc[i][j][r];
        size_t cidx = (size_t)rg * ldc + (size_t)z * Cz + cg;
        if constexpr (EPI == 2) {
          f2bf((u16*)C_, C0 + cidx, v + ldin(bias, cg, f));
        } else if constexpr (EPI == 3) {
          f2bf((u16*)C_, C0 + cidx, v);
        } else {
          float mk = maskp[(size_t)rg * 6 + z];
          if (mk > 0.5f) {
            float o = v + bf2f(hyp, cidx);
            if (f) f2bf((u16*)C_, C0 + cidx, o);
            else   reinterpret_cast<float*>(C_)[C0 + cidx] = o;
          } else {
            if (f) reinterpret_cast<u16*>(C_)[C0 + cidx] =
                       reinterpret_cast<const u16*>(hsp)[C0 + cidx];
            else   reinterpret_cast<float*>(C_)[C0 + cidx] =
                       reinterpret_cast<const float*>(hsp)[C0 + cidx];
          }
        }
      }
    }
  }
}

// ------- tiled transpose to bf16: out[z][n][k] = cvt(in[z][k][n]) -----------
__global__ __launch_bounds__(256)
void rim_transpose(const void* __restrict__ in, u16* __restrict__ out,
                   int N, int K, long in_z, long out_z,
                   const int* __restrict__ flagp)
{
  const int f = flagp[0];
  __shared__ float tile[32][33];
  int z = blockIdx.z;
  int k0 = blockIdx.x * 32, n0 = blockIdx.y * 32;
  int c = threadIdx.x & 31, r = threadIdx.x >> 5;
  for (int rr = r; rr < 32; rr += 8) {
    int k = k0 + rr, n = n0 + c;
    tile[rr][c] = (k < K && n < N)
        ? ldin(in, (size_t)z * in_z + (size_t)k * N + n, f) : 0.f;
  }
  __syncthreads();
  for (int rr = r; rr < 32; rr += 8) {
    int n = n0 + rr, k = k0 + c;
    if (n < N && k < K)
      f2bf(out, (size_t)z * out_z + (size_t)n * K + k, tile[c][rr]);
  }
}

// ------- combined GRU weight, tiled transpose: out[u][o][i]=sum_s sw*gw[s][i][o]
__global__ __launch_bounds__(256)
void rim_gruw(const void* __restrict__ sw, const void* __restrict__ gw,
              u16* __restrict__ out, int IVH, const int* __restrict__ flagp)
{
  const int f = flagp[0];
  __shared__ float lds[64 * 17];
  int u = blockIdx.z;
  int i0 = blockIdx.x * 16, o0 = blockIdx.y * 64;
  int t = threadIdx.x;
  float s0 = ldin(sw, u * 4 + 0, f), s1 = ldin(sw, u * 4 + 1, f);
  float s2 = ldin(sw, u * 4 + 2, f), s3 = ldin(sw, u * 4 + 3, f);
  int oo = t & 63, iq = t >> 6;
  size_t pl = (size_t)IVH * 1536;
#pragma unroll
  for (int r = 0; r < 4; r++) {
    int ii = iq * 4 + r;
    size_t base = (size_t)(i0 + ii) * 1536 + o0 + oo;
    float acc = s0 * ldin(gw, base, f) + s1 * ldin(gw, pl + base, f) +
                s2 * ldin(gw, 2 * pl + base, f) + s3 * ldin(gw, 3 * pl + base, f);
    lds[oo * 17 + ii] = acc;
  }
  __syncthreads();
  int ow = t >> 2, iw = (t & 3) * 4;
  u16x4 pk;
#pragma unroll
  for (int j = 0; j < 4; j++) pk[j] = bfbits(lds[ow * 17 + iw + j]);
  *reinterpret_cast<u16x4*>(out + ((size_t)u * 1536 + o0 + ow) * IVH + i0 + iw) = pk;
}

// ---------------- scores / top-4 mask / 2-way softmax / inputs ----------------
__global__ __launch_bounds__(256)
void rim_scores(const float* __restrict__ q_l, const float* __restrict__ k_l0,
                const void* __restrict__ bk, const u16* __restrict__ v_l0,
                const void* __restrict__ bv, float* __restrict__ maskf,
                u16* __restrict__ inputs, const int* __restrict__ flagp)
{
  const int f = flagp[0];
  int b = blockIdx.x;
  int t = threadIdx.x;
  int lane = t & 63;
  __shared__ float s0[6], s1[6], sm[6], sp[6];
  if (t < 64) {
    float kv = k_l0[(size_t)b * 64 + lane];
    for (int u = 0; u < 6; u++) {
      float p = q_l[((size_t)b * 6 + u) * 64 + lane] * kv;
      for (int off = 32; off; off >>= 1) p += __shfl_down(p, off);
      if (lane == 0) s0[u] = p * 0.125f;
    }
  } else if (t < 128) {
    float kv = ldin(bk, lane, f);
    for (int u = 0; u < 6; u++) {
      float p = q_l[((size_t)b * 6 + u) * 64 + lane] * kv;
      for (int off = 32; off; off >>= 1) p += __shfl_down(p, off);
      if (lane == 0) s1[u] = p * 0.125f;
    }
  }
  __syncthreads();
  if (t == 0) {
    for (int u = 0; u < 6; u++) {
      int cnt = 0;
      for (int u2 = 0; u2 < 6; u2++)
        if (s0[u2] > s0[u] || (s0[u2] == s0[u] && u2 < u)) cnt++;
      float mk = (cnt < 4) ? 1.0f : 0.0f;
      sm[u] = mk;
      maskf[(size_t)b * 6 + u] = mk;
      sp[u] = 1.0f / (1.0f + expf(s1[u] - s0[u]));
    }
  }
  __syncthreads();
  for (int idx = t; idx < 2400; idx += 256) {
    int u = idx / 400, j = idx % 400;
    float val = sm[u] * (sp[u] * bf2f(v_l0, (size_t)b * 400 + j) +
                         (1.0f - sp[u]) * ldin(bv, j, f));
    f2bf(inputs, ((size_t)b * 6 + u) * 400 + j, val);
  }
}

// ---------------- GRU elementwise ----------------
__global__ void rim_gru(const u16* __restrict__ Ggx, const u16* __restrict__ Ggh,
                        const void* __restrict__ hs, long R0,
                        u16* __restrict__ hy, long total,
                        const int* __restrict__ flagp)
{
  const int f = flagp[0];
  long idx = (long)blockIdx.x * 256 + threadIdx.x;
  if (idx >= total) return;
  long bu = idx >> 9;
  int h = idx & 511;
  size_t gb = (size_t)bu * 1536 + h;
  float xr = bf2f(Ggx, gb), xz = bf2f(Ggx, gb + 512), xn = bf2f(Ggx, gb + 1024);
  float hr = bf2f(Ggh, gb), hz = bf2f(Ggh, gb + 512), hn = bf2f(Ggh, gb + 1024);
  float r = 1.f / (1.f + expf(-(xr + hr)));
  float zz = 1.f / (1.f + expf(-(xz + hz)));
  float n = tanhf(xn + r * hn);
  float hv = ldin(hs, R0 + idx, f);
  f2bf(hy, idx, n + zz * (hv - n));
}

// ---------------- per-b attention: att -> softmax*mask -> ctx ----------------
__global__ __launch_bounds__(256)
void rim_attn(const u16* __restrict__ qk, const float* __restrict__ maskp,
              const u16* __restrict__ v, u16* __restrict__ ctx)
{
  int bl = blockIdx.x;
  int t = threadIdx.x;
  __shared__ float qs[1536];
  __shared__ float aps[144];
  __shared__ __align__(16) u16 vs[12288];
  for (int idx = t; idx < 1536; idx += 256)
    qs[idx] = bf2f(qk, (size_t)bl * 1536 + idx);
  for (int idx = t; idx < 1536; idx += 256)
    *reinterpret_cast<bf16x8*>(&vs[idx * 8]) =
        *reinterpret_cast<const bf16x8*>(
            reinterpret_cast<const __bf16*>(v) + (size_t)bl * 12288 + idx * 8);
  __syncthreads();
  if (t < 144) {
    int h = t / 36, r6 = t % 36, uq = r6 / 6, uk = r6 % 6;
    float s = 0.f;
#pragma unroll
    for (int d = 0; d < 32; d++)
      s += qs[uq * 256 + h * 32 + d] * qs[uk * 256 + 128 + h * 32 + d];
    aps[t] = s * 0.17677669529663687f;
  }
  __syncthreads();
  if (t < 24) {
    int h = t / 6, uq = t % 6;
    float* row = &aps[h * 36 + uq * 6];
    float mx = row[0];
    for (int k = 1; k < 6; k++) mx = fmaxf(mx, row[k]);
    float e[6], sum = 0.f;
    for (int k = 0; k < 6; k++) { e[k] = expf(row[k] - mx); sum += e[k]; }
    float mk = maskp[(size_t)bl * 6 + uq] / sum;
    for (int k = 0; k < 6; k++) row[k] = e[k] * mk;
  }
  __syncthreads();
  for (int idx = t; idx < 12288; idx += 256) {
    int uq = idx >> 11, g = idx & 2047, h = g >> 9;
    const float* ar = &aps[h * 36 + uq * 6];
    float acc = 0.f;
#pragma unroll
    for (int k = 0; k < 6; k++) acc += ar[k] * bf2f(vs, k * 2048 + g);
    f2bf(ctx, ((size_t)bl * 6 + uq) * 2048 + g, acc);
  }
}

// ---------------- host ----------------
extern "C" void kernel_launch(void* const* d_in, const int* in_sizes, int n_in,
                              void* d_out, int out_size, void* d_ws, size_t ws_size,
                              hipStream_t stream)
{
  (void)in_sizes; (void)n_in; (void)out_size;
  const void* x   = d_in[0];
  const void* hs  = d_in[1];
  const void* Wk  = d_in[2];
  const void* bk  = d_in[3];
  const void* Wv  = d_in[4];
  const void* bv  = d_in[5];
  const void* Wq  = d_in[6];
  const void* Wq_ = d_in[7];
  const void* Wk_ = d_in[8];
  const void* Wv_ = d_in[9];
  const void* Wo_ = d_in[10];
  const void* sw  = d_in[11];
  const void* gwx = d_in[12];
  const void* gwh = d_in[13];
  char* ws = (char*)d_ws;

  int*   flagp = (int*)(ws + OFF_FLAG);
  float* maskf = (float*)(ws + OFF_MASK);
  u16* WvT   = (u16*)(ws + OFF_WVT);
  u16* WqkT  = (u16*)(ws + OFF_WQKT);
  u16* WvT_  = (u16*)(ws + OFF_WVT_);
  u16* WoT   = (u16*)(ws + OFF_WOT);
  u16* WxcT  = (u16*)(ws + OFF_WXCT);
  u16* WhcT  = (u16*)(ws + OFF_WHCT);
  u16* hy    = (u16*)(ws + OFF_HY);
  u16* inputs = (u16*)(ws + A_INP);
  float* PK   = (float*)(ws + A_PK);
  float* PQ   = (float*)(ws + A_PQ);
  float* k_l0 = (float*)(ws + A_KL);
  float* q_l  = (float*)(ws + A_QL);
  u16* v_l0   = (u16*)(ws + A_VL);

  int R2 = 256, R3 = 256;
  {
    const int cand[5] = {4096, 2048, 1024, 512, 256};
    for (int i = 0; i < 5; i++)
      if (A_P1 + (size_t)cand[i] * 36864 <= ws_size) { R2 = cand[i]; break; }
    for (int i = 0; i < 5; i++)
      if (ARENA + (size_t)cand[i] * 52224 <= ws_size) { R3 = cand[i]; break; }
  }

  rim_detect<<<dim3(1), dim3(64), 0, stream>>>(sw, flagp);

  auto T = [&](const void* in, u16* outp, int N, int K, long iz, long oz, int Z) {
    dim3 g((K + 31) / 32, (N + 31) / 32, Z);
    rim_transpose<<<g, dim3(256), 0, stream>>>(in, outp, N, K, iz, oz, flagp);
  };
  T(Wv, WvT, 400, 1024, 0, 0, 1);
  T(Wq_, WqkT, 128, 512, 65536, 131072, 6);
  T(Wk_, WqkT + 65536, 128, 512, 65536, 131072, 6);
  T(Wv_, WvT_, 2048, 512, 1048576, 1048576, 6);
  T(Wo_, WoT, 512, 2048, 1048576, 1048576, 6);
  rim_gruw<<<dim3(25, 24, 6), dim3(256), 0, stream>>>(sw, gwx, WxcT, 400, flagp);
  rim_gruw<<<dim3(32, 24, 6), dim3(256), 0, stream>>>(sw, gwh, WhcT, 512, flagp);

  auto G = [&](int epi, int adt, const void* A, long A0, long lda, long Az,
               const u16* B, long Bz, void* C, long C0, long ldc, long Cz,
               int M, int N, int K, int Z,
               const void* bias, const u16* hyp, const float* mp, const void* hsp) {
    dim3 g((M + 127) / 128, (N + 127) / 128, Z), blk(256);
    if (epi == 2 && adt == 1)
      rim_gemm<2, 1><<<g, blk, 0, stream>>>(A, A0, lda, Az, B, Bz, C, C0, ldc, Cz, M, N, K, bias, hyp, mp, hsp, flagp);
    else if (epi == 3 && adt == 1)
      rim_gemm<3, 1><<<g, blk, 0, stream>>>(A, A0, lda, Az, B, Bz, C, C0, ldc, Cz, M, N, K, bias, hyp, mp, hsp, flagp);
    else if (epi == 3 && adt == 0)
      rim_gemm<3, 0><<<g, blk, 0, stream>>>(A, A0, lda, Az, B, Bz, C, C0, ldc, Cz, M, N, K, bias, hyp, mp, hsp, flagp);
    else
      rim_gemm<4, 0><<<g, blk, 0, stream>>>(A, A0, lda, Az, B, Bz, C, C0, ldc, Cz, M, N, K, bias, hyp, mp, hsp, flagp);
  };

  // scores path: f32 split-K SGEMM (exact products -> stable top-k)
  rim_sgemm32<<<dim3(128, 4, 1), dim3(256), 0, stream>>>(
      x, 1024, 0, Wk, 0, PK, 256, flagp);
  rim_sgemm32<<<dim3(128, 2, 6), dim3(256), 0, stream>>>(
      hs, 3072, 512, Wq, 32768, PQ, 256, flagp);
  rim_sreduce<<<dim3(1024), dim3(256), 0, stream>>>(
      PK, 4, 1, k_l0, 64, 0, bk, flagp, 4096L * 64);
  rim_sreduce<<<dim3(6144), dim3(256), 0, stream>>>(
      PQ, 2, 6, q_l, 384, 64, nullptr, flagp, 6L * 4096 * 64);
  G(2, 1, x, 0, 1024, 0, WvT, 0, v_l0, 0, 400, 0, 4096, 400, 1024, 1,
    bv, nullptr, nullptr, nullptr);
  rim_scores<<<dim3(4096), dim3(256), 0, stream>>>(q_l, k_l0, bk, v_l0, bv,
                                                   maskf, inputs, flagp);

  // GRU in chunks of R2 rows
  u16* Ggx = (u16*)(ws + A_P1);
  u16* Ggh = (u16*)(ws + A_P1 + (size_t)R2 * 18432);
  for (int r0 = 0; r0 < 4096; r0 += R2) {
    G(3, 1, hs, (long)r0 * 3072, 3072, 512, WhcT, 786432, Ggh, 0, 9216, 1536,
      R2, 1536, 512, 6, nullptr, nullptr, nullptr, nullptr);
    G(3, 0, inputs, (long)r0 * 2400, 2400, 400, WxcT, 614400, Ggx, 0, 9216, 1536,
      R2, 1536, 400, 6, nullptr, nullptr, nullptr, nullptr);
    long total = (long)R2 * 3072;
    rim_gru<<<dim3((unsigned)(total / 256)), dim3(256), 0, stream>>>(
        Ggx, Ggh, hs, (long)r0 * 3072, hy + (size_t)r0 * 3072, total, flagp);
  }

  // attention + output in chunks of R3 rows
  u16* qk_c  = (u16*)(ws + ARENA);
  u16* v_c   = (u16*)(ws + ARENA + (size_t)R3 * 3072);
  u16* ctx_c = (u16*)(ws + ARENA + (size_t)R3 * 3072 + (size_t)R3 * 24576);
  for (int r0 = 0; r0 < 4096; r0 += R3) {
    G(3, 0, hy, (long)r0 * 3072, 3072, 512, WqkT, 131072, qk_c, 0, 1536, 256,
      R3, 256, 512, 6, nullptr, nullptr, nullptr, nullptr);
    G(3, 0, hy, (long)r0 * 3072, 3072, 512, WvT_, 1048576, v_c, 0, 12288, 2048,
      R3, 2048, 512, 6, nullptr, nullptr, nullptr, nullptr);
    rim_attn<<<dim3(R3), dim3(256), 0, stream>>>(qk_c, maskf + (size_t)r0 * 6, v_c, ctx_c);
    G(4, 0, ctx_c, 0, 12288, 2048, WoT, 1048576, d_out, (long)r0 * 3072, 3072, 512,
      R3, 512, 2048, 6, nullptr, hy + (size_t)r0 * 3072, maskf + (size_t)r0 * 6, hs);
  }
}